// Round 2
// baseline (69.738 us; speedup 1.0000x reference)
//
#include <hip/hip_runtime.h>
#include <math.h>

#define N 8192
#define BS 256
#define NBLK (N / 32)   // 256 blocks, each owns 32 consecutive i's
#define EPSV 1e-8f

// Single-dispatch Cox partial-likelihood loss.
// Each block stages ALL of t[] and exp(risk[]) into LDS (64 KB -> 1 block/CU),
// computes complete risk-set sums S_i for its 32 i's (8 per wave, lanes slice
// the 8192 j's as float4), then applies log + event mask and atomicAdd's its
// scalar partial into out[0] (harness zeroes out before launch).
// No grid sync, no workspace, no second dispatch.
__global__ __launch_bounds__(BS) void cox_all(const float* __restrict__ risk,
                                              const float* __restrict__ t,
                                              const float* __restrict__ e,
                                              float* __restrict__ out) {
    __shared__ float sT[N];
    __shared__ float sE[N];

    const int tid = threadIdx.x;

    // ---- stage all of t and exp(risk) into LDS, float4-vectorized ----
    const float4* t4g = (const float4*)t;
    const float4* r4g = (const float4*)risk;
    float4* sT4 = (float4*)sT;
    float4* sE4 = (float4*)sE;
    #pragma unroll
    for (int s = 0; s < N / 4 / BS; ++s) {   // 8 iterations
        int fl = tid + s * BS;
        float4 tv = t4g[fl];
        float4 rv = r4g[fl];
        sT4[fl] = tv;
        float4 ev;
        ev.x = __expf(rv.x);
        ev.y = __expf(rv.y);
        ev.z = __expf(rv.z);
        ev.w = __expf(rv.w);
        sE4[fl] = ev;
    }

    const int lane = tid & 63;
    const int wave = tid >> 6;
    const int i0 = blockIdx.x * 32 + wave * 8;   // this wave's 8 i's

    __syncthreads();

    // t_i from LDS (uniform address per wave -> broadcast, no conflict)
    float ti[8];
    #pragma unroll
    for (int m = 0; m < 8; ++m) ti[m] = sT[i0 + m];

    float sum[8];
    #pragma unroll
    for (int m = 0; m < 8; ++m) sum[m] = 0.0f;

    // ---- main loop: 32 float4-iterations per lane covers all 8192 j's ----
    #pragma unroll 4
    for (int k = 0; k < N / 4 / 64; ++k) {       // 32 iterations
        int f = lane + (k << 6);
        float4 tj = sT4[f];
        float4 ej = sE4[f];
        #pragma unroll
        for (int m = 0; m < 8; ++m) {
            float s0 = (tj.x >= ti[m]) ? ej.x : 0.0f;
            float s1 = (tj.y >= ti[m]) ? ej.y : 0.0f;
            float s2 = (tj.z >= ti[m]) ? ej.z : 0.0f;
            float s3 = (tj.w >= ti[m]) ? ej.w : 0.0f;
            sum[m] += (s0 + s1) + (s2 + s3);
        }
    }

    // ---- reduce each of the 8 sums across the 64 lanes ----
    float myS = 0.0f;
    #pragma unroll
    for (int m = 0; m < 8; ++m) {
        float v = sum[m];
        v += __shfl_xor(v, 32);
        v += __shfl_xor(v, 16);
        v += __shfl_xor(v, 8);
        v += __shfl_xor(v, 4);
        v += __shfl_xor(v, 2);
        v += __shfl_xor(v, 1);
        if (lane == m) myS = v;   // lane m keeps S for i = i0+m
    }

    // ---- per-i loss contribution on lanes 0-7, reduce within the 8-group ----
    float c = 0.0f;
    if (lane < 8) {
        int i = i0 + lane;
        c = e[i] * (risk[i] - __logf(myS + EPSV));
    }
    // xor-reduce mixes only within each aligned 8-lane group; lanes 8-63 sum zeros
    c += __shfl_xor(c, 4);
    c += __shfl_xor(c, 2);
    c += __shfl_xor(c, 1);

    __shared__ float sW[4];
    if (lane == 0) sW[wave] = c;
    __syncthreads();
    if (tid == 0) {
        float tot = (sW[0] + sW[1]) + (sW[2] + sW[3]);
        atomicAdd(out, -tot * (1.0f / (float)N));
    }
}

extern "C" void kernel_launch(void* const* d_in, const int* in_sizes, int n_in,
                              void* d_out, int out_size, void* d_ws, size_t ws_size,
                              hipStream_t stream) {
    const float* risk = (const float*)d_in[0];
    const float* t    = (const float*)d_in[1];
    const float* e    = (const float*)d_in[2];
    float* out  = (float*)d_out;

    cox_all<<<dim3(NBLK), dim3(BS), 0, stream>>>(risk, t, e, out);
}